// Round 3
// baseline (582.481 us; speedup 1.0000x reference)
//
#include <hip/hip_runtime.h>
#include <hip/hip_bf16.h>

#define S_LEN 1024
#define DK 64
#define QB 32
#define NW 16            // waves per block
#define KSL 64           // k-slice per wave

typedef __attribute__((ext_vector_type(8))) short bf16x8;
typedef __attribute__((ext_vector_type(16))) float f32x16;
typedef __attribute__((ext_vector_type(4))) int i32x4;

__device__ __forceinline__ unsigned short f2bf(float f) {
    __hip_bfloat16 h = __float2bfloat16(f);
    unsigned short u; __builtin_memcpy(&u, &h, 2);
    return u;
}
__device__ __forceinline__ unsigned int pack2(float a, float b) {
    return (unsigned int)f2bf(a) | ((unsigned int)f2bf(b) << 16);
}
__device__ __forceinline__ bf16x8 load_cvt8(const float* p, float scale) {
    float4 a = *(const float4*)p;
    float4 b = *(const float4*)(p + 4);
    bf16x8 r;
    r[0] = (short)f2bf(a.x * scale); r[1] = (short)f2bf(a.y * scale);
    r[2] = (short)f2bf(a.z * scale); r[3] = (short)f2bf(a.w * scale);
    r[4] = (short)f2bf(b.x * scale); r[5] = (short)f2bf(b.y * scale);
    r[6] = (short)f2bf(b.z * scale); r[7] = (short)f2bf(b.w * scale);
    return r;
}

__global__ __launch_bounds__(1024, 4)
void sdpa_kernel(const float* __restrict__ Q, const float* __restrict__ K,
                 const float* __restrict__ V, const int* __restrict__ M,
                 float* __restrict__ OC, float* __restrict__ OA)
{
    __shared__ float cbuf[QB * DK];      // 8 KB ctx accumulator
    __shared__ float wsum[NW * 32];      // per-wave row sums
    __shared__ float invl[32];

    const int bid = blockIdx.x;
    const int lin = (bid & 7) * 256 + (bid >> 3);   // XCD swizzle (2048 = 8*256)
    const int head = lin >> 5;            // 0..63
    const int q0 = (lin & 31) * QB;

    const int tid = threadIdx.x;
    const int wv = tid >> 6;              // 0..15
    const int lo = tid & 31;
    const int hi = (tid >> 5) & 1;

    // zero ctx accumulator (visible to all after first barrier)
    *(float2*)(cbuf + tid * 2) = float2{0.f, 0.f};

    // ---- Q fragments (B operand): lane holds Q[q0+lo][s*16 + 8*hi + j], pre-scaled
    const float* qptr = Q + (size_t)(head * S_LEN + q0 + lo) * DK + hi * 8;
    bf16x8 qf[4];
#pragma unroll
    for (int s = 0; s < 4; ++s) qf[s] = load_cvt8(qptr + s * 16, 0.125f);

    // ---- swapped QK^T: acc[t][r] = S^T[k][q],  k = wv*64 + t*32 + (r&3)+8*(r>>2)+4*hi, q = q0+lo
    f32x16 acc[2];
    const float* kbase = K + (size_t)head * S_LEN * DK;
#pragma unroll
    for (int t = 0; t < 2; ++t) {
        const float* kptr = kbase + (wv * KSL + t * 32 + lo) * DK + hi * 8;
        f32x16 a;
#pragma unroll
        for (int i = 0; i < 16; ++i) a[i] = 0.f;
#pragma unroll
        for (int s = 0; s < 4; ++s) {
            bf16x8 kf = load_cvt8(kptr + s * 16, 1.f);
            a = __builtin_amdgcn_mfma_f32_32x32x16_bf16(kf, qf[s], a, 0, 0, 0);
        }
        acc[t] = a;
    }

    // ---- mask (per-lane int4, k-runs of 4 match C-layout) + exp; masked -> 0
    const int* mrowp = M + (size_t)(head * S_LEN + q0 + lo) * S_LEN + wv * KSL + hi * 4;
    float lsum = 0.f;
#pragma unroll
    for (int t = 0; t < 2; ++t) {
#pragma unroll
        for (int rq = 0; rq < 4; ++rq) {
            i32x4 mv = __builtin_nontemporal_load((const i32x4*)(mrowp + t * 32 + rq * 8));
            float e0 = mv[0] ? 0.f : __expf(acc[t][rq * 4 + 0]);
            float e1 = mv[1] ? 0.f : __expf(acc[t][rq * 4 + 1]);
            float e2 = mv[2] ? 0.f : __expf(acc[t][rq * 4 + 2]);
            float e3 = mv[3] ? 0.f : __expf(acc[t][rq * 4 + 3]);
            acc[t][rq * 4 + 0] = e0; acc[t][rq * 4 + 1] = e1;
            acc[t][rq * 4 + 2] = e2; acc[t][rq * 4 + 3] = e3;
            lsum += (e0 + e1) + (e2 + e3);
        }
    }

    // ---- row sum: lane-local + partner half + cross-wave LDS
    lsum += __shfl_xor(lsum, 32, 64);
    if (hi == 0) wsum[wv * 32 + lo] = lsum;
    __syncthreads();
    if (tid < 32) {
        float tot = 0.f;
#pragma unroll
        for (int w = 0; w < NW; ++w) tot += wsum[w * 32 + tid];
        invl[tid] = 1.f / tot;
    }
    __syncthreads();
    const float sc = invl[lo];

    // ---- normalize + attn store (float4 per lane; lane owns row q0+lo)
    float* arow = OA + (size_t)(head * S_LEN + q0 + lo) * S_LEN + wv * KSL + hi * 4;
#pragma unroll
    for (int t = 0; t < 2; ++t) {
#pragma unroll
        for (int rq = 0; rq < 4; ++rq) {
            float4 pn;
            pn.x = acc[t][rq * 4 + 0] * sc;
            pn.y = acc[t][rq * 4 + 1] * sc;
            pn.z = acc[t][rq * 4 + 2] * sc;
            pn.w = acc[t][rq * 4 + 3] * sc;
            acc[t][rq * 4 + 0] = pn.x; acc[t][rq * 4 + 1] = pn.y;
            acc[t][rq * 4 + 2] = pn.z; acc[t][rq * 4 + 3] = pn.w;
            *(float4*)(arow + t * 32 + rq * 8) = pn;
        }
    }

    // ---- build PV A-fragments in-register: pack to bf16 pairs, swap hi-halves
    bf16x8 pa[4];
#pragma unroll
    for (int t = 0; t < 2; ++t) {
        unsigned int W0 = pack2(acc[t][0],  acc[t][1]);
        unsigned int W1 = pack2(acc[t][2],  acc[t][3]);
        unsigned int W2 = pack2(acc[t][4],  acc[t][5]);
        unsigned int W3 = pack2(acc[t][6],  acc[t][7]);
        unsigned int W4 = pack2(acc[t][8],  acc[t][9]);
        unsigned int W5 = pack2(acc[t][10], acc[t][11]);
        unsigned int W6 = pack2(acc[t][12], acc[t][13]);
        unsigned int W7 = pack2(acc[t][14], acc[t][15]);
        unsigned int X0 = __shfl_xor(W0, 32, 64);
        unsigned int X1 = __shfl_xor(W1, 32, 64);
        unsigned int X2 = __shfl_xor(W2, 32, 64);
        unsigned int X3 = __shfl_xor(W3, 32, 64);
        unsigned int X4 = __shfl_xor(W4, 32, 64);
        unsigned int X5 = __shfl_xor(W5, 32, 64);
        unsigned int X6 = __shfl_xor(W6, 32, 64);
        unsigned int X7 = __shfl_xor(W7, 32, 64);
        uint4 f0, f1;
        f0.x = hi ? X2 : W0;  f0.y = hi ? X3 : W1;
        f0.z = hi ? W2 : X0;  f0.w = hi ? W3 : X1;
        f1.x = hi ? X6 : W4;  f1.y = hi ? X7 : W5;
        f1.z = hi ? W6 : X4;  f1.w = hi ? W7 : X5;
        pa[t * 2 + 0] = __builtin_bit_cast(bf16x8, f0);
        pa[t * 2 + 1] = __builtin_bit_cast(bf16x8, f1);
    }

    // ---- PV partial over this wave's 64-k slice
    f32x16 pv0, pv1;
#pragma unroll
    for (int i = 0; i < 16; ++i) { pv0[i] = 0.f; pv1[i] = 0.f; }
    const float* vbase = V + (size_t)head * S_LEN * DK;
#pragma unroll
    for (int s = 0; s < 4; ++s) {
        const float* vp = vbase + (wv * KSL + s * 16 + hi * 8) * DK;
        bf16x8 v0, v1;
#pragma unroll
        for (int j = 0; j < 8; ++j) {
            v0[j] = (short)f2bf(vp[j * DK + lo]);
            v1[j] = (short)f2bf(vp[j * DK + 32 + lo]);
        }
        pv0 = __builtin_amdgcn_mfma_f32_32x32x16_bf16(pa[s], v0, pv0, 0, 0, 0);
        pv1 = __builtin_amdgcn_mfma_f32_32x32x16_bf16(pa[s], v1, pv1, 0, 0, 0);
    }

    // ---- cross-wave ctx reduce via LDS float atomics
#pragma unroll
    for (int r = 0; r < 16; ++r) {
        const int q = (r & 3) + 8 * (r >> 2) + 4 * hi;
        atomicAdd(&cbuf[q * DK + lo], pv0[r]);
        atomicAdd(&cbuf[q * DK + 32 + lo], pv1[r]);
    }
    __syncthreads();

    // ---- coalesced context store (2 floats per thread)
    {
        float2 s2 = *(const float2*)(cbuf + tid * 2);
        const int row = tid >> 5;
        const int col = (tid * 2) & 63;
        *(float2*)(OC + (size_t)(head * S_LEN + q0 + row) * DK + col) = s2;
    }
}

extern "C" void kernel_launch(void* const* d_in, const int* in_sizes, int n_in,
                              void* d_out, int out_size, void* d_ws, size_t ws_size,
                              hipStream_t stream) {
    const float* Q = (const float*)d_in[0];
    const float* K = (const float*)d_in[1];
    const float* V = (const float*)d_in[2];
    const int*   M = (const int*)d_in[3];
    float* OC = (float*)d_out;                       // context: 4*16*1024*64
    float* OA = OC + 4 * 16 * 1024 * 64;             // attn:    4*16*1024*1024
    sdpa_kernel<<<dim3(2048), dim3(1024), 0, stream>>>(Q, K, V, M, OC, OA);
}

// Round 4
// 457.357 us; speedup vs baseline: 1.2736x; 1.2736x over previous
//
#include <hip/hip_runtime.h>
#include <hip/hip_bf16.h>

#define S_LEN 1024
#define DK 64
#define NW 8

typedef __attribute__((ext_vector_type(8))) short bf16x8;
typedef __attribute__((ext_vector_type(16))) float f32x16;

__device__ __forceinline__ unsigned short f2bf(float f) {
    __hip_bfloat16 h = __float2bfloat16(f);
    unsigned short u; __builtin_memcpy(&u, &h, 2);
    return u;
}
__device__ __forceinline__ bf16x8 load_cvt8(const float* p, float scale) {
    float4 a = *(const float4*)p;
    float4 b = *(const float4*)(p + 4);
    bf16x8 r;
    r[0] = (short)f2bf(a.x * scale); r[1] = (short)f2bf(a.y * scale);
    r[2] = (short)f2bf(a.z * scale); r[3] = (short)f2bf(a.w * scale);
    r[4] = (short)f2bf(b.x * scale); r[5] = (short)f2bf(b.y * scale);
    r[6] = (short)f2bf(b.z * scale); r[7] = (short)f2bf(b.w * scale);
    return r;
}

__global__ __launch_bounds__(512, 4)
void sdpa_kernel(const float* __restrict__ Q, const float* __restrict__ K,
                 const float* __restrict__ V, const int* __restrict__ M,
                 float* __restrict__ OC, float* __restrict__ OA)
{
    __shared__ unsigned long long mlds[32 * 17];        // 4352 B mask bits (stride 17 u64)
    __shared__ unsigned short    plds[NW * 32 * 64];    // 32 KB P half-tiles (bf16)
    __shared__ float             cbuf[32 * DK];         // 8 KB ctx accumulator
    __shared__ float             wsum[NW * 32];
    __shared__ float             invl[32];

    const int bid  = blockIdx.x;
    const int lin  = (bid & 7) * 256 + (bid >> 3);      // XCD swizzle
    const int head = lin >> 5;
    const int q0   = (lin & 31) * 32;

    const int tid  = threadIdx.x;
    const int wv   = tid >> 6;
    const int lane = tid & 63;
    const int lo   = tid & 31;
    const int hi   = (tid >> 5) & 1;

    // zero ctx accumulator (ordered before use by barrier #1)
    *(float4*)(cbuf + tid * 4) = float4{0.f, 0.f, 0.f, 0.f};

    // ---- Q fragments (A operand): row=lane&31=q, contraction d = s*16 + 8*hi + j
    const float* qptr = Q + (size_t)(head * S_LEN + q0 + lo) * DK + hi * 8;
    bf16x8 qf[4];
#pragma unroll
    for (int s = 0; s < 4; ++s) qf[s] = load_cvt8(qptr + s * 16, 0.125f);

    // ---- Phase 0: ballot-pack this wave's 4 mask rows into LDS bits
    {
        const int* mb = M + (size_t)(head * S_LEN + q0 + wv * 4) * S_LEN;
#pragma unroll
        for (int r4 = 0; r4 < 4; ++r4) {
            int mv[16];
#pragma unroll
            for (int s = 0; s < 16; ++s)
                mv[s] = __builtin_nontemporal_load(mb + r4 * S_LEN + s * 64 + lane);
            unsigned long long bal[16];
#pragma unroll
            for (int s = 0; s < 16; ++s) bal[s] = __ballot(mv[s] != 0);
            if (lane == 0) {
#pragma unroll
                for (int s = 0; s < 16; ++s) mlds[(wv * 4 + r4) * 17 + s] = bal[s];
            }
        }
    }

    // ---- QK^T: wave's 32q x 128k slice, 4 tiles x 4 K-steps
    f32x16 acc[4];
    const float* kbase = K + (size_t)head * S_LEN * DK;
#pragma unroll
    for (int t = 0; t < 4; ++t) {
        const float* kptr = kbase + (size_t)(wv * 128 + t * 32 + lo) * DK + hi * 8;
        f32x16 a;
#pragma unroll
        for (int i = 0; i < 16; ++i) a[i] = 0.f;
#pragma unroll
        for (int s = 0; s < 4; ++s) {
            bf16x8 kf = load_cvt8(kptr + s * 16, 1.f);
            a = __builtin_amdgcn_mfma_f32_32x32x16_bf16(qf[s], kf, a, 0, 0, 0);
        }
        acc[t] = a;
    }

    __syncthreads();   // mask LDS + cbuf zero visible

    // ---- mask test (broadcast u32 + bit extract) + exp + per-row partial sums
    const unsigned* m32 = (const unsigned*)mlds;        // row stride 34 u32
    float rs[16];
#pragma unroll
    for (int r = 0; r < 16; ++r) rs[r] = 0.f;
#pragma unroll
    for (int t = 0; t < 4; ++t) {
#pragma unroll
        for (int r = 0; r < 16; ++r) {
            const int row = (r & 3) + 8 * (r >> 2) + 4 * hi;
            const unsigned mw = m32[row * 34 + wv * 4 + t];
            const float e = ((mw >> lo) & 1u) ? 0.f : __expf(acc[t][r]);
            acc[t][r] = e;
            rs[r] += e;
        }
    }

    // ---- cross-lane (32) butterfly sum, then cross-wave via LDS
#pragma unroll
    for (int r = 0; r < 16; ++r) {
        float v = rs[r];
        v += __shfl_xor(v, 1, 64);
        v += __shfl_xor(v, 2, 64);
        v += __shfl_xor(v, 4, 64);
        v += __shfl_xor(v, 8, 64);
        v += __shfl_xor(v, 16, 64);
        if (lo == 0) wsum[wv * 32 + ((r & 3) + 8 * (r >> 2) + 4 * hi)] = v;
    }
    __syncthreads();
    if (tid < 32) {
        float tot = 0.f;
#pragma unroll
        for (int w = 0; w < NW; ++w) tot += wsum[w * 32 + tid];
        invl[tid] = 1.f / tot;
    }
    __syncthreads();

    // ---- per k-half: normalize + attn store + P->LDS pack, then PV MFMAs
    float* arow = OA + (size_t)(head * S_LEN + q0) * S_LEN;
    unsigned short* Pw = plds + wv * (32 * 64);
    const float* vbase = V + (size_t)head * S_LEN * DK;
    f32x16 pv0, pv1;
#pragma unroll
    for (int i = 0; i < 16; ++i) { pv0[i] = 0.f; pv1[i] = 0.f; }

#pragma unroll
    for (int h = 0; h < 2; ++h) {
#pragma unroll
        for (int t2 = 0; t2 < 2; ++t2) {
            const int t = h * 2 + t2;
#pragma unroll
            for (int r = 0; r < 16; ++r) {
                const int row = (r & 3) + 8 * (r >> 2) + 4 * hi;
                const float pn = acc[t][r] * invl[row];
                arow[(size_t)row * S_LEN + wv * 128 + t * 32 + lo] = pn;
                const int off = (row * 128 + (t2 * 32 + lo) * 2) ^ ((row & 7) << 4);
                *(unsigned short*)((char*)Pw + off) = f2bf(pn);
            }
        }
        // same-wave DS in-order: reads below see the writes above
#pragma unroll
        for (int st = 0; st < 4; ++st) {
            const int off = (lo * 128 + (st * 16 + hi * 8) * 2) ^ ((lo & 7) << 4);
            bf16x8 af = *(const bf16x8*)((const char*)Pw + off);
            const float* vp = vbase + (size_t)(wv * 128 + h * 64 + st * 16 + hi * 8) * DK;
            bf16x8 v0, v1;
#pragma unroll
            for (int j = 0; j < 8; ++j) {
                v0[j] = (short)f2bf(vp[j * DK + lo]);
                v1[j] = (short)f2bf(vp[j * DK + 32 + lo]);
            }
            pv0 = __builtin_amdgcn_mfma_f32_32x32x16_bf16(af, v0, pv0, 0, 0, 0);
            pv1 = __builtin_amdgcn_mfma_f32_32x32x16_bf16(af, v1, pv1, 0, 0, 0);
        }
    }

    // ---- cross-wave ctx reduce via LDS atomics
#pragma unroll
    for (int r = 0; r < 16; ++r) {
        const int q = (r & 3) + 8 * (r >> 2) + 4 * hi;
        atomicAdd(&cbuf[q * DK + lo], pv0[r]);
        atomicAdd(&cbuf[q * DK + 32 + lo], pv1[r]);
    }
    __syncthreads();

    // ---- coalesced context store (float4 per thread)
    {
        float4 s4 = *(const float4*)(cbuf + tid * 4);
        const int row = tid >> 4;
        const int col = (tid * 4) & 63;
        *(float4*)(OC + (size_t)(head * S_LEN + q0 + row) * DK + col) = s4;
    }
}

extern "C" void kernel_launch(void* const* d_in, const int* in_sizes, int n_in,
                              void* d_out, int out_size, void* d_ws, size_t ws_size,
                              hipStream_t stream) {
    const float* Q = (const float*)d_in[0];
    const float* K = (const float*)d_in[1];
    const float* V = (const float*)d_in[2];
    const int*   M = (const int*)d_in[3];
    float* OC = (float*)d_out;                       // context: 4*16*1024*64
    float* OA = OC + 4 * 16 * 1024 * 64;             // attn:    4*16*1024*1024
    sdpa_kernel<<<dim3(2048), dim3(512), 0, stream>>>(Q, K, V, M, OC, OA);
}

// Round 5
// 436.575 us; speedup vs baseline: 1.3342x; 1.0476x over previous
//
#include <hip/hip_runtime.h>
#include <hip/hip_bf16.h>

#define S_LEN 1024
#define DK 64
#define NW 8

typedef __attribute__((ext_vector_type(8))) short bf16x8;
typedef __attribute__((ext_vector_type(16))) float f32x16;
typedef __attribute__((ext_vector_type(4))) float f32x4;

__device__ __forceinline__ unsigned short f2bf(float f) {
    __hip_bfloat16 h = __float2bfloat16(f);
    unsigned short u; __builtin_memcpy(&u, &h, 2);
    return u;
}
__device__ __forceinline__ bf16x8 load_cvt8(const float* p, float scale) {
    float4 a = *(const float4*)p;
    float4 b = *(const float4*)(p + 4);
    bf16x8 r;
    r[0] = (short)f2bf(a.x * scale); r[1] = (short)f2bf(a.y * scale);
    r[2] = (short)f2bf(a.z * scale); r[3] = (short)f2bf(a.w * scale);
    r[4] = (short)f2bf(b.x * scale); r[5] = (short)f2bf(b.y * scale);
    r[6] = (short)f2bf(b.z * scale); r[7] = (short)f2bf(b.w * scale);
    return r;
}

__global__ __launch_bounds__(512, 4)
void sdpa_kernel(const float* __restrict__ Q, const float* __restrict__ K,
                 const float* __restrict__ V, const int* __restrict__ M,
                 float* __restrict__ OC, float* __restrict__ OA)
{
    __shared__ unsigned long long mlds[32 * 17];        // 4352 B mask bits (stride 17 u64)
    __shared__ unsigned short    plds[NW * 32 * 64];    // 32 KB P half-tiles (bf16)
    __shared__ float             cbuf[32 * DK];         // 8 KB ctx accumulator
    __shared__ float             wsum[NW * 32];
    __shared__ float             invl[32];

    const int bid  = blockIdx.x;
    const int lin  = (bid & 7) * 256 + (bid >> 3);      // XCD swizzle
    const int head = lin >> 5;
    const int q0   = (lin & 31) * 32;

    const int tid  = threadIdx.x;
    const int wv   = tid >> 6;
    const int lane = tid & 63;
    const int lo   = tid & 31;
    const int hi   = (tid >> 5) & 1;

    // zero ctx accumulator (ordered before use by barrier #1)
    *(float4*)(cbuf + tid * 4) = float4{0.f, 0.f, 0.f, 0.f};

    // ---- Q fragments (A operand): row=lane&31=q, contraction d = s*16 + 8*hi + j
    const float* qptr = Q + (size_t)(head * S_LEN + q0 + lo) * DK + hi * 8;
    bf16x8 qf[4];
#pragma unroll
    for (int s = 0; s < 4; ++s) qf[s] = load_cvt8(qptr + s * 16, 0.125f);

    // ---- Phase 0: ballot-pack this wave's 4 mask rows into LDS bits
    {
        const int* mb = M + (size_t)(head * S_LEN + q0 + wv * 4) * S_LEN;
#pragma unroll
        for (int r4 = 0; r4 < 4; ++r4) {
            int mv[16];
#pragma unroll
            for (int s = 0; s < 16; ++s)
                mv[s] = __builtin_nontemporal_load(mb + r4 * S_LEN + s * 64 + lane);
            unsigned long long bal[16];
#pragma unroll
            for (int s = 0; s < 16; ++s) bal[s] = __ballot(mv[s] != 0);
            if (lane == 0) {
#pragma unroll
                for (int s = 0; s < 16; ++s) mlds[(wv * 4 + r4) * 17 + s] = bal[s];
            }
        }
    }

    // ---- QK^T: wave's 32q x 128k slice, 4 tiles x 4 K-steps
    f32x16 acc[4];
    const float* kbase = K + (size_t)head * S_LEN * DK;
#pragma unroll
    for (int t = 0; t < 4; ++t) {
        const float* kptr = kbase + (size_t)(wv * 128 + t * 32 + lo) * DK + hi * 8;
        f32x16 a;
#pragma unroll
        for (int i = 0; i < 16; ++i) a[i] = 0.f;
#pragma unroll
        for (int s = 0; s < 4; ++s) {
            bf16x8 kf = load_cvt8(kptr + s * 16, 1.f);
            a = __builtin_amdgcn_mfma_f32_32x32x16_bf16(qf[s], kf, a, 0, 0, 0);
        }
        acc[t] = a;
    }

    __syncthreads();   // mask LDS + cbuf zero visible

    // ---- mask test (broadcast u32 + bit extract) + exp + per-row partial sums
    const unsigned* m32 = (const unsigned*)mlds;        // row stride 34 u32
    float rs[16];
#pragma unroll
    for (int r = 0; r < 16; ++r) rs[r] = 0.f;
#pragma unroll
    for (int t = 0; t < 4; ++t) {
#pragma unroll
        for (int r = 0; r < 16; ++r) {
            const int row = (r & 3) + 8 * (r >> 2) + 4 * hi;
            const unsigned mw = m32[row * 34 + wv * 4 + t];
            const float e = ((mw >> lo) & 1u) ? 0.f : __expf(acc[t][r]);
            acc[t][r] = e;
            rs[r] += e;
        }
    }

    // ---- cross-lane (32) butterfly sum, then cross-wave via LDS
#pragma unroll
    for (int r = 0; r < 16; ++r) {
        float v = rs[r];
        v += __shfl_xor(v, 1, 64);
        v += __shfl_xor(v, 2, 64);
        v += __shfl_xor(v, 4, 64);
        v += __shfl_xor(v, 8, 64);
        v += __shfl_xor(v, 16, 64);
        if (lo == 0) wsum[wv * 32 + ((r & 3) + 8 * (r >> 2) + 4 * hi)] = v;
    }
    __syncthreads();
    if (tid < 32) {
        float tot = 0.f;
#pragma unroll
        for (int w = 0; w < NW; ++w) tot += wsum[w * 32 + tid];
        invl[tid] = 1.f / tot;
    }
    __syncthreads();

    // ---- per k-half: normalize + attn store (nontemporal) + P->LDS pack, then PV MFMAs
    float* arow = OA + (size_t)(head * S_LEN + q0) * S_LEN;
    unsigned short* Pw = plds + wv * (32 * 64);
    const float* vbase = V + (size_t)head * S_LEN * DK;
    f32x16 pv0, pv1;
#pragma unroll
    for (int i = 0; i < 16; ++i) { pv0[i] = 0.f; pv1[i] = 0.f; }

#pragma unroll
    for (int h = 0; h < 2; ++h) {
#pragma unroll
        for (int t2 = 0; t2 < 2; ++t2) {
            const int t = h * 2 + t2;
#pragma unroll
            for (int r = 0; r < 16; ++r) {
                const int row = (r & 3) + 8 * (r >> 2) + 4 * hi;
                const float pn = acc[t][r] * invl[row];
                __builtin_nontemporal_store(pn, arow + (size_t)row * S_LEN + wv * 128 + t * 32 + lo);
                const int off = (row * 128 + (t2 * 32 + lo) * 2) ^ ((row & 7) << 4);
                *(unsigned short*)((char*)Pw + off) = f2bf(pn);
            }
        }
        // same-wave DS in-order: reads below see the writes above
#pragma unroll
        for (int st = 0; st < 4; ++st) {
            const int off = (lo * 128 + (st * 16 + hi * 8) * 2) ^ ((lo & 7) << 4);
            bf16x8 af = *(const bf16x8*)((const char*)Pw + off);
            const float* vp = vbase + (size_t)(wv * 128 + h * 64 + st * 16 + hi * 8) * DK;
            bf16x8 v0, v1;
#pragma unroll
            for (int j = 0; j < 8; ++j) {
                v0[j] = (short)f2bf(vp[j * DK + lo]);
                v1[j] = (short)f2bf(vp[j * DK + 32 + lo]);
            }
            pv0 = __builtin_amdgcn_mfma_f32_32x32x16_bf16(af, v0, pv0, 0, 0, 0);
            pv1 = __builtin_amdgcn_mfma_f32_32x32x16_bf16(af, v1, pv1, 0, 0, 0);
        }
    }

    // ---- cross-wave ctx reduce via LDS atomics
#pragma unroll
    for (int r = 0; r < 16; ++r) {
        const int q = (r & 3) + 8 * (r >> 2) + 4 * hi;
        atomicAdd(&cbuf[q * DK + lo], pv0[r]);
        atomicAdd(&cbuf[q * DK + 32 + lo], pv1[r]);
    }
    __syncthreads();

    // ---- coalesced context store (nontemporal float4 per thread)
    {
        f32x4 s4 = *(const f32x4*)(cbuf + tid * 4);
        const int row = tid >> 4;
        const int col = (tid * 4) & 63;
        __builtin_nontemporal_store(s4, (f32x4*)(OC + (size_t)(head * S_LEN + q0 + row) * DK + col));
    }
}

extern "C" void kernel_launch(void* const* d_in, const int* in_sizes, int n_in,
                              void* d_out, int out_size, void* d_ws, size_t ws_size,
                              hipStream_t stream) {
    const float* Q = (const float*)d_in[0];
    const float* K = (const float*)d_in[1];
    const float* V = (const float*)d_in[2];
    const int*   M = (const int*)d_in[3];
    float* OC = (float*)d_out;                       // context: 4*16*1024*64
    float* OA = OC + 4 * 16 * 1024 * 64;             // attn:    4*16*1024*1024
    sdpa_kernel<<<dim3(2048), dim3(512), 0, stream>>>(Q, K, V, M, OC, OA);
}

// Round 6
// 341.307 us; speedup vs baseline: 1.7066x; 1.2791x over previous
//
#include <hip/hip_runtime.h>
#include <hip/hip_bf16.h>

#define S_LEN 1024
#define DK 64
#define NW 8

typedef __attribute__((ext_vector_type(8))) short bf16x8;
typedef __attribute__((ext_vector_type(16))) float f32x16;
typedef __attribute__((ext_vector_type(4))) float f32x4;

__device__ __forceinline__ unsigned short f2bf(float f) {
    __hip_bfloat16 h = __float2bfloat16(f);
    unsigned short u; __builtin_memcpy(&u, &h, 2);
    return u;
}
__device__ __forceinline__ bf16x8 load_cvt8(const float* p, float scale) {
    float4 a = *(const float4*)p;
    float4 b = *(const float4*)(p + 4);
    bf16x8 r;
    r[0] = (short)f2bf(a.x * scale); r[1] = (short)f2bf(a.y * scale);
    r[2] = (short)f2bf(a.z * scale); r[3] = (short)f2bf(a.w * scale);
    r[4] = (short)f2bf(b.x * scale); r[5] = (short)f2bf(b.y * scale);
    r[6] = (short)f2bf(b.z * scale); r[7] = (short)f2bf(b.w * scale);
    return r;
}

__global__ __launch_bounds__(512, 2)
void sdpa_kernel(const float* __restrict__ Q, const float* __restrict__ K,
                 const float* __restrict__ V, const int* __restrict__ M,
                 float* __restrict__ OC, float* __restrict__ OA)
{
    __shared__ unsigned long long mlds[32 * 17];        // 4.25 KB mask bits
    __shared__ unsigned short    plds[NW * 32 * 128];   // 64 KB full P stash (bf16)
    __shared__ float             cbuf[32 * DK];         // 8 KB ctx accumulator
    __shared__ float             wsum[NW * 32];
    __shared__ float             invl[32];

    const int bid  = blockIdx.x;
    const int lin  = (bid & 7) * 256 + (bid >> 3);      // XCD swizzle
    const int head = lin >> 5;
    const int q0   = (lin & 31) * 32;

    const int tid  = threadIdx.x;
    const int wv   = tid >> 6;
    const int lane = tid & 63;
    const int lo   = tid & 31;
    const int hi   = (tid >> 5) & 1;

    // zero ctx accumulator (ordered before use by barrier #1)
    *(float4*)(cbuf + tid * 4) = float4{0.f, 0.f, 0.f, 0.f};

    // ---- Q fragments (A operand): row=lane&31=q, contraction d = s*16 + 8*hi + j
    const float* qptr = Q + (size_t)(head * S_LEN + q0 + lo) * DK + hi * 8;
    bf16x8 qf[4];
#pragma unroll
    for (int s = 0; s < 4; ++s) qf[s] = load_cvt8(qptr + s * 16, 0.125f);

    // ---- Phase 0: ballot-pack this wave's 4 mask rows into LDS bits
    {
        const int* mb = M + (size_t)(head * S_LEN + q0 + wv * 4) * S_LEN;
#pragma unroll
        for (int r4 = 0; r4 < 4; ++r4) {
            int mv[16];
#pragma unroll
            for (int s = 0; s < 16; ++s)
                mv[s] = __builtin_nontemporal_load(mb + r4 * S_LEN + s * 64 + lane);
            unsigned long long bal[16];
#pragma unroll
            for (int s = 0; s < 16; ++s) bal[s] = __ballot(mv[s] != 0);
            if (lane == 0) {
#pragma unroll
                for (int s = 0; s < 16; ++s) mlds[(wv * 4 + r4) * 17 + s] = bal[s];
            }
        }
    }

    // ---- QK^T: wave's 32q x 128k slice, 4 tiles x 4 K-steps
    f32x16 acc[4];
    const float* kbase = K + (size_t)head * S_LEN * DK;
#pragma unroll
    for (int t = 0; t < 4; ++t) {
        const float* kptr = kbase + (size_t)(wv * 128 + t * 32 + lo) * DK + hi * 8;
        f32x16 a;
#pragma unroll
        for (int i = 0; i < 16; ++i) a[i] = 0.f;
#pragma unroll
        for (int s = 0; s < 4; ++s) {
            bf16x8 kf = load_cvt8(kptr + s * 16, 1.f);
            a = __builtin_amdgcn_mfma_f32_32x32x16_bf16(qf[s], kf, a, 0, 0, 0);
        }
        acc[t] = a;
    }

    __syncthreads();   // mask LDS + cbuf zero visible

    // ---- mask test (broadcast u32 + bit extract) + exp + per-row partial sums
    const unsigned* m32 = (const unsigned*)mlds;        // row stride 34 u32
    float rs[16];
#pragma unroll
    for (int r = 0; r < 16; ++r) rs[r] = 0.f;
#pragma unroll
    for (int t = 0; t < 4; ++t) {
#pragma unroll
        for (int r = 0; r < 16; ++r) {
            const int row = (r & 3) + 8 * (r >> 2) + 4 * hi;
            const unsigned mw = m32[row * 34 + wv * 4 + t];
            const float e = ((mw >> lo) & 1u) ? 0.f : __expf(acc[t][r]);
            acc[t][r] = e;
            rs[r] += e;
        }
    }

    // ---- cross-lane (32) butterfly sum, then cross-wave via LDS
#pragma unroll
    for (int r = 0; r < 16; ++r) {
        float v = rs[r];
        v += __shfl_xor(v, 1, 64);
        v += __shfl_xor(v, 2, 64);
        v += __shfl_xor(v, 4, 64);
        v += __shfl_xor(v, 8, 64);
        v += __shfl_xor(v, 16, 64);
        if (lo == 0) wsum[wv * 32 + ((r & 3) + 8 * (r >> 2) + 4 * hi)] = v;
    }
    __syncthreads();
    if (tid < 32) {
        float tot = 0.f;
#pragma unroll
        for (int w = 0; w < NW; ++w) tot += wsum[w * 32 + tid];
        invl[tid] = 1.f / tot;
    }
    __syncthreads();

    // ---- normalize + attn store BURST (r outer, t inner: 512B region in 4
    //      consecutive instrs -> full L3 lines dirty before eviction) + P stash
    float* arow = OA + (size_t)(head * S_LEN + q0) * S_LEN;
    unsigned short* Pw = plds + wv * (32 * 128);
#pragma unroll
    for (int r = 0; r < 16; ++r) {
        const int row = (r & 3) + 8 * (r >> 2) + 4 * hi;
        const float iv = invl[row];
        float* ar = arow + (size_t)row * S_LEN + wv * 128 + lo;
#pragma unroll
        for (int t = 0; t < 4; ++t) {
            const float pn = acc[t][r] * iv;
            __builtin_nontemporal_store(pn, ar + t * 32);
            const int off = (row * 256 + (t * 32 + lo) * 2) ^ ((row & 15) << 4);
            *(unsigned short*)((char*)Pw + off) = f2bf(pn);
        }
    }

    // ---- PV over this wave's 128-k slice (all stores issued above)
    f32x16 pv0, pv1;
#pragma unroll
    for (int i = 0; i < 16; ++i) { pv0[i] = 0.f; pv1[i] = 0.f; }
    const float* vbase = V + (size_t)head * S_LEN * DK;
#pragma unroll
    for (int st = 0; st < 8; ++st) {
        const int off = (lo * 256 + st * 32 + hi * 16) ^ ((lo & 15) << 4);
        bf16x8 af = *(const bf16x8*)((const char*)Pw + off);
        const float* vp = vbase + (size_t)(wv * 128 + st * 16 + hi * 8) * DK;
        bf16x8 v0, v1;
#pragma unroll
        for (int j = 0; j < 8; ++j) {
            v0[j] = (short)f2bf(vp[j * DK + lo]);
            v1[j] = (short)f2bf(vp[j * DK + 32 + lo]);
        }
        pv0 = __builtin_amdgcn_mfma_f32_32x32x16_bf16(af, v0, pv0, 0, 0, 0);
        pv1 = __builtin_amdgcn_mfma_f32_32x32x16_bf16(af, v1, pv1, 0, 0, 0);
    }

    // ---- cross-wave ctx reduce via LDS atomics
#pragma unroll
    for (int r = 0; r < 16; ++r) {
        const int q = (r & 3) + 8 * (r >> 2) + 4 * hi;
        atomicAdd(&cbuf[q * DK + lo], pv0[r]);
        atomicAdd(&cbuf[q * DK + 32 + lo], pv1[r]);
    }
    __syncthreads();

    // ---- coalesced context store (nontemporal float4 per thread)
    {
        f32x4 s4 = *(const f32x4*)(cbuf + tid * 4);
        const int row = tid >> 4;
        const int col = (tid * 4) & 63;
        __builtin_nontemporal_store(s4, (f32x4*)(OC + (size_t)(head * S_LEN + q0 + row) * DK + col));
    }
}

extern "C" void kernel_launch(void* const* d_in, const int* in_sizes, int n_in,
                              void* d_out, int out_size, void* d_ws, size_t ws_size,
                              hipStream_t stream) {
    const float* Q = (const float*)d_in[0];
    const float* K = (const float*)d_in[1];
    const float* V = (const float*)d_in[2];
    const int*   M = (const int*)d_in[3];
    float* OC = (float*)d_out;                       // context: 4*16*1024*64
    float* OA = OC + 4 * 16 * 1024 * 64;             // attn:    4*16*1024*1024
    sdpa_kernel<<<dim3(2048), dim3(512), 0, stream>>>(Q, K, V, M, OC, OA);
}